// Round 11
// baseline (220.835 us; speedup 1.0000x reference)
//
#include <hip/hip_runtime.h>
#include <cstdint>

#define B_    2
#define S_    2048
#define HID_  2048
#define H_    16
#define HKV_  4
#define D_    128
#define SCALE_ 0.08838834764831845f   // 1/sqrt(128)
#define LOG2E_ 1.4426950408889634f
#define K1_   (SCALE_ * LOG2E_)
#define THRS_ 62.75f                  // ~8 / K1_ : defer-max threshold (P <= 2^8)

typedef __bf16 bf16x8 __attribute__((ext_vector_type(8)));
typedef float  f32x4  __attribute__((ext_vector_type(4)));
using u16 = unsigned short;

static __device__ __forceinline__ u16 f2bf(float f) {
  union { float f; uint32_t u; } c; c.f = f;
  uint32_t u = c.u;
  return (u16)((u + 0x7FFFu + ((u >> 16) & 1u)) >> 16);  // RNE
}
static __device__ __forceinline__ float bf2f(u16 h) {
  union { uint32_t u; float f; } c; c.u = ((uint32_t)h) << 16;
  return c.f;
}
static __device__ __forceinline__ void async16(const u16* g, u16* lds) {
  __builtin_amdgcn_global_load_lds((const __attribute__((address_space(1))) void*)g,
                                   (__attribute__((address_space(3))) void*)lds, 16, 0, 0);
}

// ---------------- fused prep #1: cast x (blocks 0..8191) + weight transposes ----------------
// blocks [8192, 18432): Wq 4096 | Wk 1024 | Wv 1024 | Wo 4096 tiles of 32x32
__global__ __launch_bounds__(256) void prep_cast_weights(const float* __restrict__ x,
                                                         const float* __restrict__ Wq,
                                                         const float* __restrict__ Wk,
                                                         const float* __restrict__ Wv,
                                                         const float* __restrict__ Wo,
                                                         u16* __restrict__ xb,
                                                         u16* __restrict__ Wt,
                                                         u16* __restrict__ Wot) {
  __shared__ float tile[32][33];
  const int t = blockIdx.x;
  const int tid = threadIdx.x;
  if (t < 8192) {                       // cast x: 4 f32 per thread
    const int i = t * 256 + tid;
    float4 v = ((const float4*)x)[i];
    ushort4 o;
    o.x = f2bf(v.x); o.y = f2bf(v.y); o.z = f2bf(v.z); o.w = f2bf(v.w);
    ((ushort4*)xb)[i] = o;
    return;
  }
  const int tw = t - 8192;
  const float* W; u16* Dst; int N, lt;
  if (tw < 4096)      { W = Wq; Dst = Wt;                        N = 2048; lt = tw; }
  else if (tw < 5120) { W = Wk; Dst = Wt + (size_t)2048 * 2048;  N = 512;  lt = tw - 4096; }
  else if (tw < 6144) { W = Wv; Dst = Wt + (size_t)2560 * 2048;  N = 512;  lt = tw - 5120; }
  else                { W = Wo; Dst = Wot;                       N = 2048; lt = tw - 6144; }
  const int tx = tid & 31, ty = tid >> 5;
  const int tn = N >> 5;
  const int n0 = (lt % tn) * 32, k0 = (lt / tn) * 32;
#pragma unroll
  for (int j = 0; j < 32; j += 8)
    tile[ty + j][tx] = W[(size_t)(k0 + ty + j) * N + n0 + tx];
  __syncthreads();
#pragma unroll
  for (int j = 0; j < 32; j += 8)
    Dst[(size_t)(n0 + ty + j) * 2048 + k0 + tx] = f2bf(tile[tx][ty + j]);
}

// ---------------- fused prep #2: RoPE Q,K (vectorized pairs) + V transpose+perm ----------------
__global__ __launch_bounds__(256) void prep_rope_vt(const u16* __restrict__ qkv,
                                                    const float* __restrict__ cosb,
                                                    const float* __restrict__ sinb,
                                                    u16* __restrict__ Qr, u16* __restrict__ Kr,
                                                    u16* __restrict__ Vt) {
  __shared__ u16 tile[32][34];
  const int NQ2 = B_ * S_ * H_ * 32;    // 2,097,152
  const int NK2 = B_ * S_ * HKV_ * 32;  //   524,288
  const int blk = blockIdx.x;
  const int tid = threadIdx.x;
  if (blk < 10240) {
    const int idx = blk * 256 + tid;
    if (idx < NQ2) {
      const int j = (idx & 31) * 2, rest = idx >> 5;
      const int h = rest & 15, srow = rest >> 4;
      const int s = srow & (S_ - 1);
      const u16* base = qkv + (size_t)srow * 3072 + h * 128;
      const float2 cc = *(const float2*)&cosb[s * 128 + j];
      const float2 ss = *(const float2*)&sinb[s * 128 + j];
      const ushort2 av = *(const ushort2*)&base[j];
      const ushort2 bv = *(const ushort2*)&base[j + 64];
      const float a0 = bf2f(av.x), a1 = bf2f(av.y);
      const float b0 = bf2f(bv.x), b1 = bf2f(bv.y);
      const size_t qo = (((size_t)(srow >> 11) * H_ + h) * S_ + s) * D_;
      ushort2 lo, hi;
      lo.x = f2bf(a0 * cc.x - b0 * ss.x); lo.y = f2bf(a1 * cc.y - b1 * ss.y);
      hi.x = f2bf(b0 * cc.x + a0 * ss.x); hi.y = f2bf(b1 * cc.y + a1 * ss.y);
      *(ushort2*)&Qr[qo + j]      = lo;
      *(ushort2*)&Qr[qo + j + 64] = hi;
    } else if (idx < NQ2 + NK2) {
      const int t2 = idx - NQ2;
      const int j = (t2 & 31) * 2, rest = t2 >> 5;
      const int kv = rest & 3, srow = rest >> 2;
      const int s = srow & (S_ - 1);
      const u16* base = qkv + (size_t)srow * 3072 + 2048 + kv * 128;
      const float2 cc = *(const float2*)&cosb[s * 128 + j];
      const float2 ss = *(const float2*)&sinb[s * 128 + j];
      const ushort2 av = *(const ushort2*)&base[j];
      const ushort2 bv = *(const ushort2*)&base[j + 64];
      const float a0 = bf2f(av.x), a1 = bf2f(av.y);
      const float b0 = bf2f(bv.x), b1 = bf2f(bv.y);
      const size_t ko = (((size_t)(srow >> 11) * HKV_ + kv) * S_ + s) * D_;
      ushort2 lo, hi;
      lo.x = f2bf(a0 * cc.x - b0 * ss.x); lo.y = f2bf(a1 * cc.y - b1 * ss.y);
      hi.x = f2bf(b0 * cc.x + a0 * ss.x); hi.y = f2bf(b1 * cc.y + a1 * ss.y);
      *(ushort2*)&Kr[ko + j]      = lo;
      *(ushort2*)&Kr[ko + j + 64] = hi;
    }
    return;
  }
  // V transpose + kv-pair permute: lt in [0, 2048)
  const int lt = blk - 10240;
  const int bx = lt & 3, by = (lt >> 2) & 63, mat = lt >> 8;   // 4 x 64 x 8
  const int b = mat >> 2, kv = mat & 3;
  const int d0 = bx * 32, s0 = by * 32;
  const int tx = tid & 31, ty = tid >> 5;
#pragma unroll
  for (int j = 0; j < 32; j += 8)
    tile[ty + j][tx] = qkv[(size_t)(b * S_ + s0 + ty + j) * 3072 + 2560 + kv * 128 + d0 + tx];
  __syncthreads();
  const int sc  = s0 + tx;
  const int t64 = sc & 63;
  const int p   = ((t64 >> 5) * 4 + ((t64 >> 2) & 3)) * 8 + ((t64 >> 4) & 1) * 4 + (t64 & 3);
  const int scp = (sc & ~63) | p;
#pragma unroll
  for (int j = 0; j < 32; j += 8)
    Vt[((size_t)mat * D_ + d0 + ty + j) * S_ + scp] = tile[tx][ty + j];
}

// ---------------- GEMM: C(MxN) = A(MxK) bf16 * Bt(NxK)^T bf16; XCD-chunked 1-D grid ----------------
template<int BF16OUT>
__global__ __launch_bounds__(256, 4) void gemm_bt(const u16* __restrict__ A,
                                                  const u16* __restrict__ Bt,
                                                  void* __restrict__ Cv,
                                                  int M, int N, int K, int gx) {
  // bijective XCD-chunked swizzle (m204 form)
  const int nwg = (int)gridDim.x;
  const int bid = (int)blockIdx.x;
  const int qq = nwg >> 3, rr = nwg & 7;
  const int xcd = bid & 7, pos = bid >> 3;
  const int wg = ((xcd < rr) ? xcd * (qq + 1) : rr * (qq + 1) + (xcd - rr) * qq) + pos;
  const int bm = (wg % gx) * 128;
  const int bn = (wg / gx) * 128;

  __shared__ __align__(16) u16 Ash[128 * 64];
  __shared__ __align__(16) u16 Bsh[128 * 64];
  const int tid = threadIdx.x;
  const int w = tid >> 6, l = tid & 63;
  const int wm = (w >> 1) * 64, wn = (w & 1) * 64;

  const f32x4 z4 = {0.f, 0.f, 0.f, 0.f};
  f32x4 acc[4][4];
#pragma unroll
  for (int i = 0; i < 4; ++i)
#pragma unroll
    for (int j = 0; j < 4; ++j) acc[i][j] = z4;

  const int srow = w * 8 + (l >> 3);
  const int schunk = l & 7;

  for (int k0 = 0; k0 < K; k0 += 64) {
#pragma unroll
    for (int i = 0; i < 4; ++i) {
      const int row = i * 32 + srow;
      const int ch = schunk ^ (row & 7);
      async16(A + (size_t)(bm + row) * K + k0 + ch * 8, &Ash[(i * 4 + w) * 512]);
      async16(Bt + (size_t)(bn + row) * K + k0 + ch * 8, &Bsh[(i * 4 + w) * 512]);
    }
    asm volatile("s_waitcnt vmcnt(0)" ::: "memory");
    __syncthreads();
#pragma unroll
    for (int kc = 0; kc < 2; ++kc) {
      bf16x8 af[4], bfr[4];
#pragma unroll
      for (int mi = 0; mi < 4; ++mi) {
        const int r = wm + mi * 16 + (l & 15);
        const int c2 = (kc * 4 + (l >> 4)) ^ (r & 7);
        af[mi] = *(const bf16x8*)&Ash[r * 64 + c2 * 8];
      }
#pragma unroll
      for (int ni = 0; ni < 4; ++ni) {
        const int r = wn + ni * 16 + (l & 15);
        const int c2 = (kc * 4 + (l >> 4)) ^ (r & 7);
        bfr[ni] = *(const bf16x8*)&Bsh[r * 64 + c2 * 8];
      }
#pragma unroll
      for (int mi = 0; mi < 4; ++mi)
#pragma unroll
        for (int ni = 0; ni < 4; ++ni)
          acc[mi][ni] = __builtin_amdgcn_mfma_f32_16x16x32_bf16(af[mi], bfr[ni], acc[mi][ni], 0, 0, 0);
    }
    __syncthreads();
  }
#pragma unroll
  for (int mi = 0; mi < 4; ++mi) {
    const int r0 = bm + wm + mi * 16 + ((l >> 4) << 2);
#pragma unroll
    for (int ni = 0; ni < 4; ++ni) {
      const int c = bn + wn + ni * 16 + (l & 15);
#pragma unroll
      for (int j = 0; j < 4; ++j) {
        if (BF16OUT) ((u16*)Cv)[(size_t)(r0 + j) * N + c] = f2bf(acc[mi][ni][j]);
        else         ((float*)Cv)[(size_t)(r0 + j) * N + c] = acc[mi][ni][j];
      }
    }
  }
}

// ---------------- causal GQA flash attention v11 ----------------
// QBLK=128 (4 waves x 32 q-rows): each kf/vf LDS read feeds 2 MFMAs -> LDS
// traffic per unit work halved vs QBLK=64. K AND V double-buffered (64KB LDS,
// 2 blocks/CU = all 512 blocks co-resident). ONE barrier + one vmcnt(0) drain
// per tile, with stage(t+1) issued right AFTER the barrier -> full-tile hiding.
// b128 conflict-free PV (paired-kv V), panel-XCD swizzle, defer-max,
// wave-uniform masked-tile skip, complementary qt pairing.
__global__ __launch_bounds__(256, 2) void attn_kernel(const u16* __restrict__ Q,
                                                      const u16* __restrict__ Kc,
                                                      const u16* __restrict__ Vt,
                                                      u16* __restrict__ O) {
  const int bid = blockIdx.x;
  const int p   = bid & 7;              // K/V panel = b*4 + kvh  -> XCD p
  const int hs  = (bid >> 3) & 3;       // q-head within GQA group
  const int qt  = (bid < 256) ? (15 - (bid >> 5)) : ((bid >> 5) - 8);
  const int b   = p >> 2;
  const int kvh = p & 3;
  const int h   = kvh * 4 + hs;
  const int bh  = b * 16 + h;
  const int tid = threadIdx.x;
  const int w = tid >> 6, l = tid & 63;
  const int g = l >> 4, c = l & 15;
  const int q0 = qt * 128;

  __shared__ __align__(16) u16 KshF[2 * 64 * 128];   // [buf][kv][d], granule^=(kv&7)
  __shared__ __align__(16) u16 VshF[2 * 128 * 64];   // [buf][d][G'][u], G'=G^(d&7)

  const u16* Kbase = Kc + ((size_t)(b * HKV_ + kvh) * S_) * D_;   // [s][d]
  const u16* Vbase = Vt + ((size_t)(b * HKV_ + kvh) * D_) * S_;   // [d][s'] permuted

  // Q fragments (B-operand): lane holds Q[q0+w*32+qg*16+c][kc*32+g*8+j]
  bf16x8 qf[2][4];
#pragma unroll
  for (int qg = 0; qg < 2; ++qg) {
    const u16* qp = Q + ((size_t)bh * S_ + q0 + w * 32 + qg * 16 + c) * D_ + g * 8;
#pragma unroll
    for (int kc = 0; kc < 4; ++kc) qf[qg][kc] = *(const bf16x8*)(qp + kc * 32);
  }

  // staging source offsets (per-lane, per-issue i); LDS dest linear at lane*16B
  int srcK[4], srcV[4];
#pragma unroll
  for (int i = 0; i < 4; ++i) {
    const int rK = i * 16 + w * 4 + g;                  // K row this lane stages
    srcK[i] = rK * 128 + (c ^ (rK & 7)) * 8;
    const int dV = i * 32 + w * 8 + (l >> 3);           // V d-row this lane stages
    srcV[i] = dV * S_ + ((l & 7) ^ (dV & 7)) * 8;       // pre-permuted granule
  }

  const f32x4 z4 = {0.f, 0.f, 0.f, 0.f};
  f32x4 oacc[2][8];
#pragma unroll
  for (int qg = 0; qg < 2; ++qg)
#pragma unroll
    for (int nb = 0; nb < 8; ++nb) oacc[qg][nb] = z4;
  float m_i[2] = {-1e30f, -1e30f}, l_i[2] = {0.f, 0.f};

  auto stage = [&](int buf, int kv0) {
#pragma unroll
    for (int i = 0; i < 4; ++i) {
      async16(Kbase + (size_t)kv0 * 128 + srcK[i], &KshF[buf * 8192 + i * 2048 + w * 512]);
      async16(Vbase + kv0 + srcV[i],               &VshF[buf * 8192 + i * 2048 + w * 512]);
    }
  };

  const int nt = 2 * (qt + 1);
  stage(0, 0);

  for (int t = 0; t < nt; ++t) {
    const int cur = t & 1;
    const int kv0 = t << 6;
    asm volatile("s_waitcnt vmcnt(0)" ::: "memory");
    __syncthreads();                  // K(t), V(t) landed; prior reads of buf cur done
    if (t + 1 < nt) stage(cur ^ 1, (t + 1) << 6);

    // wave-uniform skip: all 32 q-rows of this wave above-masked for this tile
    if (kv0 <= q0 + w * 32 + 31) {
      const u16* Kb = &KshF[cur * 8192];

      // ---- QK^T swapped: sf[qg][nb][jj] = S[kv=kv0+nb*16+g*4+jj][q=q0+w*32+qg*16+c]
      f32x4 sf[2][4];
#pragma unroll
      for (int qg = 0; qg < 2; ++qg)
#pragma unroll
        for (int nb = 0; nb < 4; ++nb) sf[qg][nb] = z4;

      __builtin_amdgcn_s_setprio(1);
#pragma unroll
      for (int kc = 0; kc < 4; ++kc) {
#pragma unroll
        for (int nb = 0; nb < 4; ++nb) {
          const int r = nb * 16 + c;
          const int s2 = (kc * 4 + g) ^ (c & 7);          // r&7 == c&7
          const bf16x8 kf = *(const bf16x8*)&Kb[r * 128 + s2 * 8];
          sf[0][nb] = __builtin_amdgcn_mfma_f32_16x16x32_bf16(kf, qf[0][kc], sf[0][nb], 0, 0, 0);
          sf[1][nb] = __builtin_amdgcn_mfma_f32_16x16x32_bf16(kf, qf[1][kc], sf[1][nb], 0, 0, 0);
        }
      }
      __builtin_amdgcn_s_setprio(0);

      // ---- online softmax per qg (lane owns q-col); defer-max skips rescale
#pragma unroll
      for (int qg = 0; qg < 2; ++qg) {
        const int qcol = q0 + w * 32 + qg * 16 + c;
        const bool doMask = (kv0 + 63 > q0 + w * 32 + qg * 16);
        float mx = -3e38f;
#pragma unroll
        for (int nb = 0; nb < 4; ++nb)
#pragma unroll
          for (int jj = 0; jj < 4; ++jj) {
            float sv = sf[qg][nb][jj];
            if (doMask) {
              const int kk = kv0 + nb * 16 + g * 4 + jj;
              sv = (kk > qcol) ? -3e38f : sv;
              sf[qg][nb][jj] = sv;
            }
            mx = fmaxf(mx, sv);
          }
        mx = fmaxf(mx, __shfl_xor(mx, 16));
        mx = fmaxf(mx, __shfl_xor(mx, 32));

        if (__all(mx <= m_i[qg] + THRS_)) {
          const float mk = m_i[qg] * K1_;
          float rs = 0.f;
#pragma unroll
          for (int nb = 0; nb < 4; ++nb)
#pragma unroll
            for (int jj = 0; jj < 4; ++jj) {
              const float p2 = exp2f(fmaf(sf[qg][nb][jj], K1_, -mk));
              sf[qg][nb][jj] = p2;
              rs += p2;
            }
          rs += __shfl_xor(rs, 16);
          rs += __shfl_xor(rs, 32);
          l_i[qg] += rs;
        } else {
          const float mnew = fmaxf(m_i[qg], mx);
          const float fsc = exp2f((m_i[qg] - mnew) * K1_);
          m_i[qg] = mnew;
          const float mk = mnew * K1_;
          float rs = 0.f;
#pragma unroll
          for (int nb = 0; nb < 4; ++nb)
#pragma unroll
            for (int jj = 0; jj < 4; ++jj) {
              const float p2 = exp2f(fmaf(sf[qg][nb][jj], K1_, -mk));
              sf[qg][nb][jj] = p2;
              rs += p2;
            }
          rs += __shfl_xor(rs, 16);
          rs += __shfl_xor(rs, 32);
          l_i[qg] = l_i[qg] * fsc + rs;
          float fq[4];
#pragma unroll
          for (int j = 0; j < 4; ++j) fq[j] = __shfl(fsc, g * 4 + j);
#pragma unroll
          for (int nb = 0; nb < 8; ++nb)
#pragma unroll
            for (int j = 0; j < 4; ++j) oacc[qg][nb][j] *= fq[j];
        }
      }

      // ---- pack P into PV A-frags: kappa=g*8+e -> kv = kc2*32 + (e>>2)*16 + g*4 + (e&3)
      bf16x8 paq0, paq1, pbq0, pbq1;
#pragma unroll
      for (int jj = 0; jj < 4; ++jj) {
        paq0[jj] = (__bf16)sf[0][0][jj]; paq0[4 + jj] = (__bf16)sf[0][1][jj];
        pbq0[jj] = (__bf16)sf[0][2][jj]; pbq0[4 + jj] = (__bf16)sf[0][3][jj];
        paq1[jj] = (__bf16)sf[1][0][jj]; paq1[4 + jj] = (__bf16)sf[1][1][jj];
        pbq1[jj] = (__bf16)sf[1][2][jj]; pbq1[4 + jj] = (__bf16)sf[1][3][jj];
      }

      // ---- PV: B-frag = 16 contiguous bytes (paired-kv layout), XOR-swizzled b128;
      //      each vf feeds both qg MFMAs.
      const char* Vb = (const char*)&VshF[cur * 8192] + c * 128;
      __builtin_amdgcn_s_setprio(1);
#pragma unroll
      for (int kc2 = 0; kc2 < 2; ++kc2) {
        const bf16x8 pa0 = kc2 ? pbq0 : paq0;
        const bf16x8 pa1 = kc2 ? pbq1 : paq1;
        const int s2v = ((kc2 * 4 + g) ^ (c & 7)) << 4;
#pragma unroll
        for (int nb = 0; nb < 8; ++nb) {
          const bf16x8 vf = *(const bf16x8*)(Vb + nb * 2048 + s2v);
          oacc[0][nb] = __builtin_amdgcn_mfma_f32_16x16x32_bf16(pa0, vf, oacc[0][nb], 0, 0, 0);
          oacc[1][nb] = __builtin_amdgcn_mfma_f32_16x16x32_bf16(pa1, vf, oacc[1][nb], 0, 0, 0);
        }
      }
      __builtin_amdgcn_s_setprio(0);
    }
  }

  // epilogue: normalize, write O as (b, s, h*128+d) bf16
#pragma unroll
  for (int qg = 0; qg < 2; ++qg)
#pragma unroll
    for (int j = 0; j < 4; ++j) {
      const float li = __shfl(l_i[qg], g * 4 + j);
      const float inv = 1.f / li;
      const int srow = q0 + w * 32 + qg * 16 + g * 4 + j;
      u16* op = O + ((size_t)(b * S_ + srow)) * HID_ + h * D_ + c;
#pragma unroll
      for (int nb = 0; nb < 8; ++nb) op[nb * 16] = f2bf(oacc[qg][nb][j] * inv);
    }
}

// ---------------- host launch ----------------
extern "C" void kernel_launch(void* const* d_in, const int* in_sizes, int n_in,
                              void* d_out, int out_size, void* d_ws, size_t ws_size,
                              hipStream_t stream) {
  const float* x    = (const float*)d_in[0];
  const float* cosb = (const float*)d_in[1];
  const float* sinb = (const float*)d_in[2];
  const float* Wq   = (const float*)d_in[3];
  const float* Wk   = (const float*)d_in[4];
  const float* Wv   = (const float*)d_in[5];
  const float* Wo   = (const float*)d_in[6];
  float* out = (float*)d_out;

  u16*   xb   = (u16*)d_ws;                                // 4096*2048
  u16*   Wt   = xb  + (size_t)4096 * 2048;                 // 3072*2048
  u16*   Wot  = Wt  + (size_t)3072 * 2048;                 // 2048*2048
  u16*   qkv  = Wot + (size_t)2048 * 2048;                 // 4096*3072 bf16
  u16*   Qr   = qkv + (size_t)4096 * 3072;                 // (B,H,S,D)
  u16*   Kr   = Qr  + (size_t)B_ * H_ * S_ * D_;           // (B,HKV,S,D)
  u16*   Vtb  = Kr  + (size_t)B_ * HKV_ * S_ * D_;         // (B,HKV,D,S) transposed+perm
  u16*   Ob   = Vtb + (size_t)B_ * HKV_ * S_ * D_;         // (B,S,HID)

  // prep #1: cast x + all weight transposes (1 launch)
  prep_cast_weights<<<dim3(18432), 256, 0, stream>>>(x, Wq, Wk, Wv, Wo, xb, Wt, Wot);

  // QKV projection (bf16 out), 1-D grid with XCD-chunked swizzle; gx = M/128 = 32
  gemm_bt<1><<<dim3(768), 256, 0, stream>>>(xb, Wt, qkv, 4096, 3072, 2048, 32);

  // prep #2: RoPE Q,K (vectorized) + V transpose/permute (1 launch)
  prep_rope_vt<<<dim3(12288), 256, 0, stream>>>(qkv, cosb, sinb, Qr, Kr, Vtb);

  // attention: 512 blocks (QBLK=128), all co-resident, panel-XCD swizzle
  attn_kernel<<<dim3(512), 256, 0, stream>>>(Qr, Kr, Vtb, Ob);

  // output projection (f32 out)
  gemm_bt<0><<<dim3(512), 256, 0, stream>>>(Ob, Wot, out, 4096, 2048, 2048, 32);
}

// Round 12
// 198.978 us; speedup vs baseline: 1.1098x; 1.1098x over previous
//
#include <hip/hip_runtime.h>
#include <cstdint>

#define B_    2
#define S_    2048
#define HID_  2048
#define H_    16
#define HKV_  4
#define D_    128
#define SCALE_ 0.08838834764831845f   // 1/sqrt(128)
#define LOG2E_ 1.4426950408889634f
#define K1_   (SCALE_ * LOG2E_)
#define THRS_ 62.75f                  // ~8 / K1_ : defer-max threshold (P <= 2^8)

typedef __bf16 bf16x8 __attribute__((ext_vector_type(8)));
typedef float  f32x4  __attribute__((ext_vector_type(4)));
using u16 = unsigned short;

static __device__ __forceinline__ u16 f2bf(float f) {
  union { float f; uint32_t u; } c; c.f = f;
  uint32_t u = c.u;
  return (u16)((u + 0x7FFFu + ((u >> 16) & 1u)) >> 16);  // RNE
}
static __device__ __forceinline__ float bf2f(u16 h) {
  union { uint32_t u; float f; } c; c.u = ((uint32_t)h) << 16;
  return c.f;
}
static __device__ __forceinline__ void async16(const u16* g, u16* lds) {
  __builtin_amdgcn_global_load_lds((const __attribute__((address_space(1))) void*)g,
                                   (__attribute__((address_space(3))) void*)lds, 16, 0, 0);
}

// ---------------- fused prep #1: cast x (blocks 0..8191) + weight transposes ----------------
// blocks [8192, 18432): Wq 4096 | Wk 1024 | Wv 1024 | Wo 4096 tiles of 32x32
__global__ __launch_bounds__(256) void prep_cast_weights(const float* __restrict__ x,
                                                         const float* __restrict__ Wq,
                                                         const float* __restrict__ Wk,
                                                         const float* __restrict__ Wv,
                                                         const float* __restrict__ Wo,
                                                         u16* __restrict__ xb,
                                                         u16* __restrict__ Wt,
                                                         u16* __restrict__ Wot) {
  __shared__ float tile[32][33];
  const int t = blockIdx.x;
  const int tid = threadIdx.x;
  if (t < 8192) {                       // cast x: 4 f32 per thread
    const int i = t * 256 + tid;
    float4 v = ((const float4*)x)[i];
    ushort4 o;
    o.x = f2bf(v.x); o.y = f2bf(v.y); o.z = f2bf(v.z); o.w = f2bf(v.w);
    ((ushort4*)xb)[i] = o;
    return;
  }
  const int tw = t - 8192;
  const float* W; u16* Dst; int N, lt;
  if (tw < 4096)      { W = Wq; Dst = Wt;                        N = 2048; lt = tw; }
  else if (tw < 5120) { W = Wk; Dst = Wt + (size_t)2048 * 2048;  N = 512;  lt = tw - 4096; }
  else if (tw < 6144) { W = Wv; Dst = Wt + (size_t)2560 * 2048;  N = 512;  lt = tw - 5120; }
  else                { W = Wo; Dst = Wot;                       N = 2048; lt = tw - 6144; }
  const int tx = tid & 31, ty = tid >> 5;
  const int tn = N >> 5;
  const int n0 = (lt % tn) * 32, k0 = (lt / tn) * 32;
#pragma unroll
  for (int j = 0; j < 32; j += 8)
    tile[ty + j][tx] = W[(size_t)(k0 + ty + j) * N + n0 + tx];
  __syncthreads();
#pragma unroll
  for (int j = 0; j < 32; j += 8)
    Dst[(size_t)(n0 + ty + j) * 2048 + k0 + tx] = f2bf(tile[tx][ty + j]);
}

// ---------------- fused prep #2: RoPE Q,K (vectorized pairs) + V transpose+perm ----------------
__global__ __launch_bounds__(256) void prep_rope_vt(const u16* __restrict__ qkv,
                                                    const float* __restrict__ cosb,
                                                    const float* __restrict__ sinb,
                                                    u16* __restrict__ Qr, u16* __restrict__ Kr,
                                                    u16* __restrict__ Vt) {
  __shared__ u16 tile[32][34];
  const int NQ2 = B_ * S_ * H_ * 32;    // 2,097,152
  const int NK2 = B_ * S_ * HKV_ * 32;  //   524,288
  const int blk = blockIdx.x;
  const int tid = threadIdx.x;
  if (blk < 10240) {
    const int idx = blk * 256 + tid;
    if (idx < NQ2) {
      const int j = (idx & 31) * 2, rest = idx >> 5;
      const int h = rest & 15, srow = rest >> 4;
      const int s = srow & (S_ - 1);
      const u16* base = qkv + (size_t)srow * 3072 + h * 128;
      const float2 cc = *(const float2*)&cosb[s * 128 + j];
      const float2 ss = *(const float2*)&sinb[s * 128 + j];
      const ushort2 av = *(const ushort2*)&base[j];
      const ushort2 bv = *(const ushort2*)&base[j + 64];
      const float a0 = bf2f(av.x), a1 = bf2f(av.y);
      const float b0 = bf2f(bv.x), b1 = bf2f(bv.y);
      const size_t qo = (((size_t)(srow >> 11) * H_ + h) * S_ + s) * D_;
      ushort2 lo, hi;
      lo.x = f2bf(a0 * cc.x - b0 * ss.x); lo.y = f2bf(a1 * cc.y - b1 * ss.y);
      hi.x = f2bf(b0 * cc.x + a0 * ss.x); hi.y = f2bf(b1 * cc.y + a1 * ss.y);
      *(ushort2*)&Qr[qo + j]      = lo;
      *(ushort2*)&Qr[qo + j + 64] = hi;
    } else if (idx < NQ2 + NK2) {
      const int t2 = idx - NQ2;
      const int j = (t2 & 31) * 2, rest = t2 >> 5;
      const int kv = rest & 3, srow = rest >> 2;
      const int s = srow & (S_ - 1);
      const u16* base = qkv + (size_t)srow * 3072 + 2048 + kv * 128;
      const float2 cc = *(const float2*)&cosb[s * 128 + j];
      const float2 ss = *(const float2*)&sinb[s * 128 + j];
      const ushort2 av = *(const ushort2*)&base[j];
      const ushort2 bv = *(const ushort2*)&base[j + 64];
      const float a0 = bf2f(av.x), a1 = bf2f(av.y);
      const float b0 = bf2f(bv.x), b1 = bf2f(bv.y);
      const size_t ko = (((size_t)(srow >> 11) * HKV_ + kv) * S_ + s) * D_;
      ushort2 lo, hi;
      lo.x = f2bf(a0 * cc.x - b0 * ss.x); lo.y = f2bf(a1 * cc.y - b1 * ss.y);
      hi.x = f2bf(b0 * cc.x + a0 * ss.x); hi.y = f2bf(b1 * cc.y + a1 * ss.y);
      *(ushort2*)&Kr[ko + j]      = lo;
      *(ushort2*)&Kr[ko + j + 64] = hi;
    }
    return;
  }
  // V transpose + kv-pair permute: lt in [0, 2048)
  const int lt = blk - 10240;
  const int bx = lt & 3, by = (lt >> 2) & 63, mat = lt >> 8;   // 4 x 64 x 8
  const int b = mat >> 2, kv = mat & 3;
  const int d0 = bx * 32, s0 = by * 32;
  const int tx = tid & 31, ty = tid >> 5;
#pragma unroll
  for (int j = 0; j < 32; j += 8)
    tile[ty + j][tx] = qkv[(size_t)(b * S_ + s0 + ty + j) * 3072 + 2560 + kv * 128 + d0 + tx];
  __syncthreads();
  const int sc  = s0 + tx;
  const int t64 = sc & 63;
  const int p   = ((t64 >> 5) * 4 + ((t64 >> 2) & 3)) * 8 + ((t64 >> 4) & 1) * 4 + (t64 & 3);
  const int scp = (sc & ~63) | p;
#pragma unroll
  for (int j = 0; j < 32; j += 8)
    Vt[((size_t)mat * D_ + d0 + ty + j) * S_ + scp] = tile[tx][ty + j];
}

// ---------------- GEMM: C(MxN) = A(MxK) bf16 * Bt(NxK)^T bf16; XCD-chunked 1-D grid ----------------
template<int BF16OUT>
__global__ __launch_bounds__(256, 3) void gemm_bt(const u16* __restrict__ A,
                                                  const u16* __restrict__ Bt,
                                                  void* __restrict__ Cv,
                                                  int M, int N, int K, int gx) {
  // bijective XCD-chunked swizzle (m204 form)
  const int nwg = (int)gridDim.x;
  const int bid = (int)blockIdx.x;
  const int qq = nwg >> 3, rr = nwg & 7;
  const int xcd = bid & 7, pos = bid >> 3;
  const int wg = ((xcd < rr) ? xcd * (qq + 1) : rr * (qq + 1) + (xcd - rr) * qq) + pos;
  const int bm = (wg % gx) * 128;
  const int bn = (wg / gx) * 128;

  __shared__ __align__(16) u16 Ash[128 * 64];
  __shared__ __align__(16) u16 Bsh[128 * 64];
  const int tid = threadIdx.x;
  const int w = tid >> 6, l = tid & 63;
  const int wm = (w >> 1) * 64, wn = (w & 1) * 64;

  const f32x4 z4 = {0.f, 0.f, 0.f, 0.f};
  f32x4 acc[4][4];
#pragma unroll
  for (int i = 0; i < 4; ++i)
#pragma unroll
    for (int j = 0; j < 4; ++j) acc[i][j] = z4;

  const int srow = w * 8 + (l >> 3);
  const int schunk = l & 7;

  for (int k0 = 0; k0 < K; k0 += 64) {
#pragma unroll
    for (int i = 0; i < 4; ++i) {
      const int row = i * 32 + srow;
      const int ch = schunk ^ (row & 7);
      async16(A + (size_t)(bm + row) * K + k0 + ch * 8, &Ash[(i * 4 + w) * 512]);
      async16(Bt + (size_t)(bn + row) * K + k0 + ch * 8, &Bsh[(i * 4 + w) * 512]);
    }
    asm volatile("s_waitcnt vmcnt(0)" ::: "memory");
    __syncthreads();
#pragma unroll
    for (int kc = 0; kc < 2; ++kc) {
      bf16x8 af[4], bfr[4];
#pragma unroll
      for (int mi = 0; mi < 4; ++mi) {
        const int r = wm + mi * 16 + (l & 15);
        const int c2 = (kc * 4 + (l >> 4)) ^ (r & 7);
        af[mi] = *(const bf16x8*)&Ash[r * 64 + c2 * 8];
      }
#pragma unroll
      for (int ni = 0; ni < 4; ++ni) {
        const int r = wn + ni * 16 + (l & 15);
        const int c2 = (kc * 4 + (l >> 4)) ^ (r & 7);
        bfr[ni] = *(const bf16x8*)&Bsh[r * 64 + c2 * 8];
      }
#pragma unroll
      for (int mi = 0; mi < 4; ++mi)
#pragma unroll
        for (int ni = 0; ni < 4; ++ni)
          acc[mi][ni] = __builtin_amdgcn_mfma_f32_16x16x32_bf16(af[mi], bfr[ni], acc[mi][ni], 0, 0, 0);
    }
    __syncthreads();
  }
#pragma unroll
  for (int mi = 0; mi < 4; ++mi) {
    const int r0 = bm + wm + mi * 16 + ((l >> 4) << 2);
#pragma unroll
    for (int ni = 0; ni < 4; ++ni) {
      const int c = bn + wn + ni * 16 + (l & 15);
#pragma unroll
      for (int j = 0; j < 4; ++j) {
        if (BF16OUT) ((u16*)Cv)[(size_t)(r0 + j) * N + c] = f2bf(acc[mi][ni][j]);
        else         ((float*)Cv)[(size_t)(r0 + j) * N + c] = acc[mi][ni][j];
      }
    }
  }
}

// ---------------- causal GQA flash attention v12 ----------------
// v10 body (proven 72us) + balanced qt permutation: CU c hosts bids
// {c, c+256, c+512, c+768} = qt-indices {k, k+8, k+16, k+24}; map f(idx) makes
// every CU's tile total exactly 66 (v10's 31-idx gave 48..76, +-23% imbalance).
__global__ __launch_bounds__(256, 3) void attn_kernel(const u16* __restrict__ Q,
                                                      const u16* __restrict__ Kc,
                                                      const u16* __restrict__ Vt,
                                                      u16* __restrict__ O) {
  const int bid = blockIdx.x;
  const int p   = bid & 7;              // K/V panel = b*4 + kvh  -> XCD p
  const int hs  = (bid >> 3) & 3;       // q-head within GQA group
  const int idx = bid >> 5;             // 0..31
  const int grp = idx >> 3, jj2 = idx & 7;
  const int qt  = (grp == 0) ? (31 - jj2) : (grp == 1) ? jj2
                : (grp == 2) ? (23 - jj2) : (8 + jj2);
  const int b   = p >> 2;
  const int kvh = p & 3;
  const int h   = kvh * 4 + hs;
  const int bh  = b * 16 + h;
  const int tid = threadIdx.x;
  const int w = tid >> 6, l = tid & 63;
  const int g = l >> 4, c = l & 15;
  const int q0 = qt * 64;

  __shared__ __align__(16) u16 Ksh[64 * 128];        // [kv][d], granule^=(kv&7)
  __shared__ __align__(16) u16 VshF[2 * 128 * 64];   // [buf][d][G'][u], G'=G^(d&7)

  const u16* Kbase = Kc + ((size_t)(b * HKV_ + kvh) * S_) * D_;   // [s][d]
  const u16* Vbase = Vt + ((size_t)(b * HKV_ + kvh) * D_) * S_;   // [d][s'] permuted

  // Q fragments (B-operand): lane holds Q[q0+w*16+c][kc*32+g*8+j]
  bf16x8 qf[4];
  {
    const u16* qp = Q + ((size_t)bh * S_ + q0 + w * 16 + c) * D_ + g * 8;
#pragma unroll
    for (int kc = 0; kc < 4; ++kc) qf[kc] = *(const bf16x8*)(qp + kc * 32);
  }

  // staging source offsets (per-lane, per-issue i); LDS dest linear at lane*16B
  int srcK[4], srcV[4];
#pragma unroll
  for (int i = 0; i < 4; ++i) {
    const int rK = i * 16 + w * 4 + g;                  // K row this lane stages
    srcK[i] = rK * 128 + (c ^ (rK & 7)) * 8;
    const int dV = i * 32 + w * 8 + (l >> 3);           // V d-row this lane stages
    srcV[i] = dV * S_ + ((l & 7) ^ (dV & 7)) * 8;       // pre-permuted granule
  }

  const f32x4 z4 = {0.f, 0.f, 0.f, 0.f};
  f32x4 oacc[8];
#pragma unroll
  for (int nb = 0; nb < 8; ++nb) oacc[nb] = z4;
  float m_i = -1e30f, l_i = 0.f;

  auto stageK = [&](int kv0) {
#pragma unroll
    for (int i = 0; i < 4; ++i)
      async16(Kbase + (size_t)kv0 * 128 + srcK[i], &Ksh[i * 2048 + w * 512]);
  };
  auto stageV = [&](int buf, int kv0) {
#pragma unroll
    for (int i = 0; i < 4; ++i)
      async16(Vbase + kv0 + srcV[i], &VshF[buf * 8192 + i * 2048 + w * 512]);
  };

  const int nt = qt + 1;
  stageV(0, 0);
  stageK(0);

  for (int t = 0; t < nt; ++t) {
    const int cur = t & 1;
    asm volatile("s_waitcnt vmcnt(0)" ::: "memory");
    __syncthreads();                  // K(t), V(t) landed everywhere
    if (t + 1 < nt) stageV(cur ^ 1, (t + 1) << 6);

    // ---- QK^T swapped: sf[nb][jj] = S[kv=kv0+nb*16+g*4+jj][q=q0+w*16+c]
    f32x4 sf[4];
#pragma unroll
    for (int nb = 0; nb < 4; ++nb) sf[nb] = z4;

    __builtin_amdgcn_s_setprio(1);
#pragma unroll
    for (int kc = 0; kc < 4; ++kc) {
#pragma unroll
      for (int nb = 0; nb < 4; ++nb) {
        const int r = nb * 16 + c;
        const int s2 = (kc * 4 + g) ^ (c & 7);          // r&7 == c&7
        const bf16x8 kf = *(const bf16x8*)&Ksh[r * 128 + s2 * 8];
        sf[nb] = __builtin_amdgcn_mfma_f32_16x16x32_bf16(kf, qf[kc], sf[nb], 0, 0, 0);
      }
    }
    __builtin_amdgcn_s_setprio(0);

    __syncthreads();                  // all waves done reading Ksh
    if (t + 1 < nt) stageK((t + 1) << 6);

    // ---- online softmax (lane owns q-col = q0+w*16+c); defer-max skips rescale
    {
      const int kv0 = t << 6;
      const int qcol = q0 + w * 16 + c;
      const bool doMask = (t == nt - 1);
      float mx = -3e38f;
#pragma unroll
      for (int nb = 0; nb < 4; ++nb)
#pragma unroll
        for (int jj = 0; jj < 4; ++jj) {
          float sv = sf[nb][jj];
          if (doMask) {
            const int kk = kv0 + nb * 16 + g * 4 + jj;
            sv = (kk > qcol) ? -3e38f : sv;
            sf[nb][jj] = sv;
          }
          mx = fmaxf(mx, sv);
        }
      mx = fmaxf(mx, __shfl_xor(mx, 16));
      mx = fmaxf(mx, __shfl_xor(mx, 32));

      if (__all(mx <= m_i + THRS_)) {
        const float mk = m_i * K1_;
        float rs = 0.f;
#pragma unroll
        for (int nb = 0; nb < 4; ++nb)
#pragma unroll
          for (int jj = 0; jj < 4; ++jj) {
            const float p2 = exp2f(fmaf(sf[nb][jj], K1_, -mk));
            sf[nb][jj] = p2;
            rs += p2;
          }
        rs += __shfl_xor(rs, 16);
        rs += __shfl_xor(rs, 32);
        l_i += rs;
      } else {
        const float mnew = fmaxf(m_i, mx);
        const float fsc = exp2f((m_i - mnew) * K1_);
        m_i = mnew;
        const float mk = mnew * K1_;
        float rs = 0.f;
#pragma unroll
        for (int nb = 0; nb < 4; ++nb)
#pragma unroll
          for (int jj = 0; jj < 4; ++jj) {
            const float p2 = exp2f(fmaf(sf[nb][jj], K1_, -mk));
            sf[nb][jj] = p2;
            rs += p2;
          }
        rs += __shfl_xor(rs, 16);
        rs += __shfl_xor(rs, 32);
        l_i = l_i * fsc + rs;
        float fq[4];
#pragma unroll
        for (int j = 0; j < 4; ++j) fq[j] = __shfl(fsc, g * 4 + j);
#pragma unroll
        for (int nb = 0; nb < 8; ++nb)
#pragma unroll
          for (int j = 0; j < 4; ++j) oacc[nb][j] *= fq[j];
      }
    }

    // ---- pack P into PV A-frags: kappa=g*8+e -> kv = kc2*32 + (e>>2)*16 + g*4 + (e&3)
    bf16x8 pa, pb;
#pragma unroll
    for (int jj = 0; jj < 4; ++jj) {
      pa[jj] = (__bf16)sf[0][jj]; pa[4 + jj] = (__bf16)sf[1][jj];
      pb[jj] = (__bf16)sf[2][jj]; pb[4 + jj] = (__bf16)sf[3][jj];
    }

    // ---- PV: B-frag = 16 contiguous bytes (paired-kv layout), XOR-swizzled b128
    const char* Vb = (const char*)&VshF[cur * 8192] + c * 128;
    __builtin_amdgcn_s_setprio(1);
#pragma unroll
    for (int kc2 = 0; kc2 < 2; ++kc2) {
      const bf16x8 pfr = kc2 ? pb : pa;
      const int s2v = ((kc2 * 4 + g) ^ (c & 7)) << 4;
#pragma unroll
      for (int nb = 0; nb < 8; ++nb) {
        const bf16x8 vf = *(const bf16x8*)(Vb + nb * 2048 + s2v);
        oacc[nb] = __builtin_amdgcn_mfma_f32_16x16x32_bf16(pfr, vf, oacc[nb], 0, 0, 0);
      }
    }
    __builtin_amdgcn_s_setprio(0);
  }

  // epilogue: normalize, write O as (b, s, h*128+d) bf16
#pragma unroll
  for (int j = 0; j < 4; ++j) {
    const float li = __shfl(l_i, g * 4 + j);
    const float inv = 1.f / li;
    const int srow = q0 + w * 16 + g * 4 + j;
    u16* op = O + ((size_t)(b * S_ + srow)) * HID_ + h * D_ + c;
#pragma unroll
    for (int nb = 0; nb < 8; ++nb) op[nb * 16] = f2bf(oacc[nb][j] * inv);
  }
}

// ---------------- host launch ----------------
extern "C" void kernel_launch(void* const* d_in, const int* in_sizes, int n_in,
                              void* d_out, int out_size, void* d_ws, size_t ws_size,
                              hipStream_t stream) {
  const float* x    = (const float*)d_in[0];
  const float* cosb = (const float*)d_in[1];
  const float* sinb = (const float*)d_in[2];
  const float* Wq   = (const float*)d_in[3];
  const float* Wk   = (const float*)d_in[4];
  const float* Wv   = (const float*)d_in[5];
  const float* Wo   = (const float*)d_in[6];
  float* out = (float*)d_out;

  u16*   xb   = (u16*)d_ws;                                // 4096*2048
  u16*   Wt   = xb  + (size_t)4096 * 2048;                 // 3072*2048
  u16*   Wot  = Wt  + (size_t)3072 * 2048;                 // 2048*2048
  u16*   qkv  = Wot + (size_t)2048 * 2048;                 // 4096*3072 bf16
  u16*   Qr   = qkv + (size_t)4096 * 3072;                 // (B,H,S,D)
  u16*   Kr   = Qr  + (size_t)B_ * H_ * S_ * D_;           // (B,HKV,S,D)
  u16*   Vtb  = Kr  + (size_t)B_ * HKV_ * S_ * D_;         // (B,HKV,D,S) transposed+perm
  u16*   Ob   = Vtb + (size_t)B_ * HKV_ * S_ * D_;         // (B,S,HID)

  // prep #1: cast x + all weight transposes (1 launch)
  prep_cast_weights<<<dim3(18432), 256, 0, stream>>>(x, Wq, Wk, Wv, Wo, xb, Wt, Wot);

  // QKV projection (bf16 out), 1-D grid with XCD-chunked swizzle; gx = M/128 = 32
  gemm_bt<1><<<dim3(768), 256, 0, stream>>>(xb, Wt, qkv, 4096, 3072, 2048, 32);

  // prep #2: RoPE Q,K (vectorized) + V transpose/permute (1 launch)
  prep_rope_vt<<<dim3(12288), 256, 0, stream>>>(qkv, cosb, sinb, Qr, Kr, Vtb);

  // attention: 1024 blocks, panel-XCD swizzle, balanced per-CU qt permutation
  attn_kernel<<<dim3(1024), 256, 0, stream>>>(Qr, Kr, Vtb, Ob);

  // output projection (f32 out)
  gemm_bt<0><<<dim3(512), 256, 0, stream>>>(Ob, Wot, out, 4096, 2048, 2048, 32);
}

// Round 13
// 195.528 us; speedup vs baseline: 1.1294x; 1.0176x over previous
//
#include <hip/hip_runtime.h>
#include <cstdint>

#define B_    2
#define S_    2048
#define HID_  2048
#define H_    16
#define HKV_  4
#define D_    128
#define SCALE_ 0.08838834764831845f   // 1/sqrt(128)
#define LOG2E_ 1.4426950408889634f
#define K1_   (SCALE_ * LOG2E_)
#define THRS_ 62.75f                  // ~8 / K1_ : defer-max threshold (P <= 2^8)

typedef __bf16 bf16x8 __attribute__((ext_vector_type(8)));
typedef float  f32x4  __attribute__((ext_vector_type(4)));
using u16 = unsigned short;

static __device__ __forceinline__ u16 f2bf(float f) {
  union { float f; uint32_t u; } c; c.f = f;
  uint32_t u = c.u;
  return (u16)((u + 0x7FFFu + ((u >> 16) & 1u)) >> 16);  // RNE
}
static __device__ __forceinline__ float bf2f(u16 h) {
  union { uint32_t u; float f; } c; c.u = ((uint32_t)h) << 16;
  return c.f;
}
static __device__ __forceinline__ void async16(const u16* g, u16* lds) {
  __builtin_amdgcn_global_load_lds((const __attribute__((address_space(1))) void*)g,
                                   (__attribute__((address_space(3))) void*)lds, 16, 0, 0);
}

// ---------------- fused prep #1: cast x (blocks 0..8191) + weight transposes ----------------
// blocks [8192, 18432): Wq 4096 | Wk 1024 | Wv 1024 | Wo 4096 tiles of 32x32
__global__ __launch_bounds__(256) void prep_cast_weights(const float* __restrict__ x,
                                                         const float* __restrict__ Wq,
                                                         const float* __restrict__ Wk,
                                                         const float* __restrict__ Wv,
                                                         const float* __restrict__ Wo,
                                                         u16* __restrict__ xb,
                                                         u16* __restrict__ Wt,
                                                         u16* __restrict__ Wot) {
  __shared__ float tile[32][33];
  const int t = blockIdx.x;
  const int tid = threadIdx.x;
  if (t < 8192) {                       // cast x: 4 f32 per thread
    const int i = t * 256 + tid;
    float4 v = ((const float4*)x)[i];
    ushort4 o;
    o.x = f2bf(v.x); o.y = f2bf(v.y); o.z = f2bf(v.z); o.w = f2bf(v.w);
    ((ushort4*)xb)[i] = o;
    return;
  }
  const int tw = t - 8192;
  const float* W; u16* Dst; int N, lt;
  if (tw < 4096)      { W = Wq; Dst = Wt;                        N = 2048; lt = tw; }
  else if (tw < 5120) { W = Wk; Dst = Wt + (size_t)2048 * 2048;  N = 512;  lt = tw - 4096; }
  else if (tw < 6144) { W = Wv; Dst = Wt + (size_t)2560 * 2048;  N = 512;  lt = tw - 5120; }
  else                { W = Wo; Dst = Wot;                       N = 2048; lt = tw - 6144; }
  const int tx = tid & 31, ty = tid >> 5;
  const int tn = N >> 5;
  const int n0 = (lt % tn) * 32, k0 = (lt / tn) * 32;
#pragma unroll
  for (int j = 0; j < 32; j += 8)
    tile[ty + j][tx] = W[(size_t)(k0 + ty + j) * N + n0 + tx];
  __syncthreads();
#pragma unroll
  for (int j = 0; j < 32; j += 8)
    Dst[(size_t)(n0 + ty + j) * 2048 + k0 + tx] = f2bf(tile[tx][ty + j]);
}

// ---------------- prep #2: K-RoPE only (Q fused into attn, V fused into gemm1) ----------------
__global__ __launch_bounds__(256) void prep_rope_k(const u16* __restrict__ qkv,
                                                   const float* __restrict__ cosb,
                                                   const float* __restrict__ sinb,
                                                   u16* __restrict__ Kr) {
  const int idx = blockIdx.x * 256 + threadIdx.x;   // < 524288
  const int j = (idx & 31) * 2, rest = idx >> 5;
  const int kv = rest & 3, srow = rest >> 2;
  const int s = srow & (S_ - 1);
  const u16* base = qkv + (size_t)srow * 3072 + 2048 + kv * 128;
  const float2 cc = *(const float2*)&cosb[s * 128 + j];
  const float2 ss = *(const float2*)&sinb[s * 128 + j];
  const ushort2 av = *(const ushort2*)&base[j];
  const ushort2 bv = *(const ushort2*)&base[j + 64];
  const float a0 = bf2f(av.x), a1 = bf2f(av.y);
  const float b0 = bf2f(bv.x), b1 = bf2f(bv.y);
  const size_t ko = (((size_t)(srow >> 11) * HKV_ + kv) * S_ + s) * D_;
  ushort2 lo, hi;
  lo.x = f2bf(a0 * cc.x - b0 * ss.x); lo.y = f2bf(a1 * cc.y - b1 * ss.y);
  hi.x = f2bf(b0 * cc.x + a0 * ss.x); hi.y = f2bf(b1 * cc.y + a1 * ss.y);
  *(ushort2*)&Kr[ko + j]      = lo;
  *(ushort2*)&Kr[ko + j + 64] = hi;
}

// ---------------- GEMM: C(MxN) = A(MxK) bf16 * Bt(NxK)^T bf16; XCD-chunked 1-D grid ----------------
// MODE 0: f32 C out. MODE 1: qkv producer — Q/K tiles (bn<2560) -> bf16 qkv;
// V tiles (bn>=2560) -> transposed + kv-pair-permuted Vt directly.
template<int MODE>
__global__ __launch_bounds__(256, 3) void gemm_bt(const u16* __restrict__ A,
                                                  const u16* __restrict__ Bt,
                                                  void* __restrict__ Cv,
                                                  u16* __restrict__ Vt,
                                                  int M, int N, int K, int gx) {
  // bijective XCD-chunked swizzle (m204 form)
  const int nwg = (int)gridDim.x;
  const int bid = (int)blockIdx.x;
  const int qq = nwg >> 3, rr = nwg & 7;
  const int xcd = bid & 7, pos = bid >> 3;
  const int wg = ((xcd < rr) ? xcd * (qq + 1) : rr * (qq + 1) + (xcd - rr) * qq) + pos;
  const int bm = (wg % gx) * 128;
  const int bn = (wg / gx) * 128;

  __shared__ __align__(16) u16 Ash[128 * 64];
  __shared__ __align__(16) u16 Bsh[128 * 64];
  const int tid = threadIdx.x;
  const int w = tid >> 6, l = tid & 63;
  const int wm = (w >> 1) * 64, wn = (w & 1) * 64;

  const f32x4 z4 = {0.f, 0.f, 0.f, 0.f};
  f32x4 acc[4][4];
#pragma unroll
  for (int i = 0; i < 4; ++i)
#pragma unroll
    for (int j = 0; j < 4; ++j) acc[i][j] = z4;

  const int srow = w * 8 + (l >> 3);
  const int schunk = l & 7;

  for (int k0 = 0; k0 < K; k0 += 64) {
#pragma unroll
    for (int i = 0; i < 4; ++i) {
      const int row = i * 32 + srow;
      const int ch = schunk ^ (row & 7);
      async16(A + (size_t)(bm + row) * K + k0 + ch * 8, &Ash[(i * 4 + w) * 512]);
      async16(Bt + (size_t)(bn + row) * K + k0 + ch * 8, &Bsh[(i * 4 + w) * 512]);
    }
    asm volatile("s_waitcnt vmcnt(0)" ::: "memory");
    __syncthreads();
#pragma unroll
    for (int kc = 0; kc < 2; ++kc) {
      bf16x8 af[4], bfr[4];
#pragma unroll
      for (int mi = 0; mi < 4; ++mi) {
        const int r = wm + mi * 16 + (l & 15);
        const int c2 = (kc * 4 + (l >> 4)) ^ (r & 7);
        af[mi] = *(const bf16x8*)&Ash[r * 64 + c2 * 8];
      }
#pragma unroll
      for (int ni = 0; ni < 4; ++ni) {
        const int r = wn + ni * 16 + (l & 15);
        const int c2 = (kc * 4 + (l >> 4)) ^ (r & 7);
        bfr[ni] = *(const bf16x8*)&Bsh[r * 64 + c2 * 8];
      }
#pragma unroll
      for (int mi = 0; mi < 4; ++mi)
#pragma unroll
        for (int ni = 0; ni < 4; ++ni)
          acc[mi][ni] = __builtin_amdgcn_mfma_f32_16x16x32_bf16(af[mi], bfr[ni], acc[mi][ni], 0, 0, 0);
    }
    __syncthreads();
  }

  if (MODE == 1 && bn >= 2560) {
    // V tile: write transposed + kv-pair-permuted Vt[mat][d][s'] as ushort4
    const int kv = (bn - 2560) >> 7;
#pragma unroll
    for (int mi = 0; mi < 4; ++mi) {
      const int r0 = bm + wm + mi * 16 + ((l >> 4) << 2);
      const int bb = r0 >> 11;
      const int s0 = r0 & (S_ - 1);
      const int a  = (s0 & 63) >> 2;
      const int pb = ((a >> 3) * 4 + (a & 3)) * 8 + ((a >> 2) & 1) * 4;
      const int spb = (s0 & ~63) | pb;
      u16* vb = Vt + ((size_t)(bb * HKV_ + kv) * D_) * S_ + spb;
#pragma unroll
      for (int ni = 0; ni < 4; ++ni) {
        const int d = wn + ni * 16 + (l & 15);
        ushort4 o;
        o.x = f2bf(acc[mi][ni][0]); o.y = f2bf(acc[mi][ni][1]);
        o.z = f2bf(acc[mi][ni][2]); o.w = f2bf(acc[mi][ni][3]);
        *(ushort4*)&vb[(size_t)d * S_] = o;
      }
    }
  } else {
#pragma unroll
    for (int mi = 0; mi < 4; ++mi) {
      const int r0 = bm + wm + mi * 16 + ((l >> 4) << 2);
#pragma unroll
      for (int ni = 0; ni < 4; ++ni) {
        const int c = bn + wn + ni * 16 + (l & 15);
#pragma unroll
        for (int j = 0; j < 4; ++j) {
          if (MODE == 1) ((u16*)Cv)[(size_t)(r0 + j) * N + c] = f2bf(acc[mi][ni][j]);
          else           ((float*)Cv)[(size_t)(r0 + j) * N + c] = acc[mi][ni][j];
        }
      }
    }
  }
}

// ---------------- causal GQA flash attention v13 ----------------
// r12 body (proven 72us) + Q-RoPE fused into the prologue (reads qkv directly;
// pair (d, d+64) = qf[kc] / qf[kc^2] in the SAME lane -> no cross-lane traffic).
__global__ __launch_bounds__(256, 3) void attn_kernel(const u16* __restrict__ qkv,
                                                      const float* __restrict__ cosb,
                                                      const float* __restrict__ sinb,
                                                      const u16* __restrict__ Kc,
                                                      const u16* __restrict__ Vt,
                                                      u16* __restrict__ O) {
  const int bid = blockIdx.x;
  const int p   = bid & 7;              // K/V panel = b*4 + kvh  -> XCD p
  const int hs  = (bid >> 3) & 3;       // q-head within GQA group
  const int idx = bid >> 5;             // 0..31
  const int grp = idx >> 3, jj2 = idx & 7;
  const int qt  = (grp == 0) ? (31 - jj2) : (grp == 1) ? jj2
                : (grp == 2) ? (23 - jj2) : (8 + jj2);
  const int b   = p >> 2;
  const int kvh = p & 3;
  const int h   = kvh * 4 + hs;
  const int tid = threadIdx.x;
  const int w = tid >> 6, l = tid & 63;
  const int g = l >> 4, c = l & 15;
  const int q0 = qt * 64;

  __shared__ __align__(16) u16 Ksh[64 * 128];        // [kv][d], granule^=(kv&7)
  __shared__ __align__(16) u16 VshF[2 * 128 * 64];   // [buf][d][G'][u], G'=G^(d&7)

  const u16* Kbase = Kc + ((size_t)(b * HKV_ + kvh) * S_) * D_;   // [s][d]
  const u16* Vbase = Vt + ((size_t)(b * HKV_ + kvh) * D_) * S_;   // [d][s'] permuted

  // Q fragments with fused RoPE: lane holds Q[q0+w*16+c][kc*32+g*8+j]
  bf16x8 qf[4];
  {
    const int s_q = q0 + w * 16 + c;
    const u16* qp = qkv + (size_t)(b * S_ + s_q) * 3072 + h * 128 + g * 8;
    bf16x8 qraw[4];
#pragma unroll
    for (int kc = 0; kc < 4; ++kc) qraw[kc] = *(const bf16x8*)(qp + kc * 32);
    const float* cp = cosb + s_q * 128 + g * 8;
    const float* sp = sinb + s_q * 128 + g * 8;
#pragma unroll
    for (int kcp = 0; kcp < 2; ++kcp) {
      // cos/sin[d] == cos/sin[d+64] (rope tables concat), d = kcp*32+g*8+j
      float cl[8], sl[8];
      *(float4*)&cl[0] = *(const float4*)(cp + kcp * 32);
      *(float4*)&cl[4] = *(const float4*)(cp + kcp * 32 + 4);
      *(float4*)&sl[0] = *(const float4*)(sp + kcp * 32);
      *(float4*)&sl[4] = *(const float4*)(sp + kcp * 32 + 4);
      bf16x8 lo, hi;
#pragma unroll
      for (int j = 0; j < 8; ++j) {
        const float a  = (float)qraw[kcp][j];        // d in [0,64)
        const float b2 = (float)qraw[kcp + 2][j];    // d+64
        lo[j] = (__bf16)(a * cl[j] - b2 * sl[j]);
        hi[j] = (__bf16)(b2 * cl[j] + a * sl[j]);
      }
      qf[kcp] = lo; qf[kcp + 2] = hi;
    }
  }

  // staging source offsets (per-lane, per-issue i); LDS dest linear at lane*16B
  int srcK[4], srcV[4];
#pragma unroll
  for (int i = 0; i < 4; ++i) {
    const int rK = i * 16 + w * 4 + g;                  // K row this lane stages
    srcK[i] = rK * 128 + (c ^ (rK & 7)) * 8;
    const int dV = i * 32 + w * 8 + (l >> 3);           // V d-row this lane stages
    srcV[i] = dV * S_ + ((l & 7) ^ (dV & 7)) * 8;       // pre-permuted granule
  }

  const f32x4 z4 = {0.f, 0.f, 0.f, 0.f};
  f32x4 oacc[8];
#pragma unroll
  for (int nb = 0; nb < 8; ++nb) oacc[nb] = z4;
  float m_i = -1e30f, l_i = 0.f;

  auto stageK = [&](int kv0) {
#pragma unroll
    for (int i = 0; i < 4; ++i)
      async16(Kbase + (size_t)kv0 * 128 + srcK[i], &Ksh[i * 2048 + w * 512]);
  };
  auto stageV = [&](int buf, int kv0) {
#pragma unroll
    for (int i = 0; i < 4; ++i)
      async16(Vbase + kv0 + srcV[i], &VshF[buf * 8192 + i * 2048 + w * 512]);
  };

  const int nt = qt + 1;
  stageV(0, 0);
  stageK(0);

  for (int t = 0; t < nt; ++t) {
    const int cur = t & 1;
    asm volatile("s_waitcnt vmcnt(0)" ::: "memory");
    __syncthreads();                  // K(t), V(t) landed everywhere
    if (t + 1 < nt) stageV(cur ^ 1, (t + 1) << 6);

    // ---- QK^T swapped: sf[nb][jj] = S[kv=kv0+nb*16+g*4+jj][q=q0+w*16+c]
    f32x4 sf[4];
#pragma unroll
    for (int nb = 0; nb < 4; ++nb) sf[nb] = z4;

    __builtin_amdgcn_s_setprio(1);
#pragma unroll
    for (int kc = 0; kc < 4; ++kc) {
#pragma unroll
      for (int nb = 0; nb < 4; ++nb) {
        const int r = nb * 16 + c;
        const int s2 = (kc * 4 + g) ^ (c & 7);          // r&7 == c&7
        const bf16x8 kf = *(const bf16x8*)&Ksh[r * 128 + s2 * 8];
        sf[nb] = __builtin_amdgcn_mfma_f32_16x16x32_bf16(kf, qf[kc], sf[nb], 0, 0, 0);
      }
    }
    __builtin_amdgcn_s_setprio(0);

    __syncthreads();                  // all waves done reading Ksh
    if (t + 1 < nt) stageK((t + 1) << 6);

    // ---- online softmax (lane owns q-col = q0+w*16+c); defer-max skips rescale
    {
      const int kv0 = t << 6;
      const int qcol = q0 + w * 16 + c;
      const bool doMask = (t == nt - 1);
      float mx = -3e38f;
#pragma unroll
      for (int nb = 0; nb < 4; ++nb)
#pragma unroll
        for (int jj = 0; jj < 4; ++jj) {
          float sv = sf[nb][jj];
          if (doMask) {
            const int kk = kv0 + nb * 16 + g * 4 + jj;
            sv = (kk > qcol) ? -3e38f : sv;
            sf[nb][jj] = sv;
          }
          mx = fmaxf(mx, sv);
        }
      mx = fmaxf(mx, __shfl_xor(mx, 16));
      mx = fmaxf(mx, __shfl_xor(mx, 32));

      if (__all(mx <= m_i + THRS_)) {
        const float mk = m_i * K1_;
        float rs = 0.f;
#pragma unroll
        for (int nb = 0; nb < 4; ++nb)
#pragma unroll
          for (int jj = 0; jj < 4; ++jj) {
            const float p2 = exp2f(fmaf(sf[nb][jj], K1_, -mk));
            sf[nb][jj] = p2;
            rs += p2;
          }
        rs += __shfl_xor(rs, 16);
        rs += __shfl_xor(rs, 32);
        l_i += rs;
      } else {
        const float mnew = fmaxf(m_i, mx);
        const float fsc = exp2f((m_i - mnew) * K1_);
        m_i = mnew;
        const float mk = mnew * K1_;
        float rs = 0.f;
#pragma unroll
        for (int nb = 0; nb < 4; ++nb)
#pragma unroll
          for (int jj = 0; jj < 4; ++jj) {
            const float p2 = exp2f(fmaf(sf[nb][jj], K1_, -mk));
            sf[nb][jj] = p2;
            rs += p2;
          }
        rs += __shfl_xor(rs, 16);
        rs += __shfl_xor(rs, 32);
        l_i = l_i * fsc + rs;
        float fq[4];
#pragma unroll
        for (int j = 0; j < 4; ++j) fq[j] = __shfl(fsc, g * 4 + j);
#pragma unroll
        for (int nb = 0; nb < 8; ++nb)
#pragma unroll
          for (int j = 0; j < 4; ++j) oacc[nb][j] *= fq[j];
      }
    }

    // ---- pack P into PV A-frags: kappa=g*8+e -> kv = kc2*32 + (e>>2)*16 + g*4 + (e&3)
    bf16x8 pa, pb;
#pragma unroll
    for (int jj = 0; jj < 4; ++jj) {
      pa[jj] = (__bf16)sf[0][jj]; pa[4 + jj] = (__bf16)sf[1][jj];
      pb[jj] = (__bf16)sf[2][jj]; pb[4 + jj] = (__bf16)sf[3][jj];
    }

    // ---- PV: B-frag = 16 contiguous bytes (paired-kv layout), XOR-swizzled b128
    const char* Vb = (const char*)&VshF[cur * 8192] + c * 128;
    __builtin_amdgcn_s_setprio(1);
#pragma unroll
    for (int kc2 = 0; kc2 < 2; ++kc2) {
      const bf16x8 pfr = kc2 ? pb : pa;
      const int s2v = ((kc2 * 4 + g) ^ (c & 7)) << 4;
#pragma unroll
      for (int nb = 0; nb < 8; ++nb) {
        const bf16x8 vf = *(const bf16x8*)(Vb + nb * 2048 + s2v);
        oacc[nb] = __builtin_amdgcn_mfma_f32_16x16x32_bf16(pfr, vf, oacc[nb], 0, 0, 0);
      }
    }
    __builtin_amdgcn_s_setprio(0);
  }

  // epilogue: normalize, write O as (b, s, h*128+d) bf16
#pragma unroll
  for (int j = 0; j < 4; ++j) {
    const float li = __shfl(l_i, g * 4 + j);
    const float inv = 1.f / li;
    const int srow = q0 + w * 16 + g * 4 + j;
    u16* op = O + ((size_t)(b * S_ + srow)) * HID_ + h * D_ + c;
#pragma unroll
    for (int nb = 0; nb < 8; ++nb) op[nb * 16] = f2bf(oacc[nb][j] * inv);
  }
}

// ---------------- host launch ----------------
extern "C" void kernel_launch(void* const* d_in, const int* in_sizes, int n_in,
                              void* d_out, int out_size, void* d_ws, size_t ws_size,
                              hipStream_t stream) {
  const float* x    = (const float*)d_in[0];
  const float* cosb = (const float*)d_in[1];
  const float* sinb = (const float*)d_in[2];
  const float* Wq   = (const float*)d_in[3];
  const float* Wk   = (const float*)d_in[4];
  const float* Wv   = (const float*)d_in[5];
  const float* Wo   = (const float*)d_in[6];
  float* out = (float*)d_out;

  u16*   xb   = (u16*)d_ws;                                // 4096*2048
  u16*   Wt   = xb  + (size_t)4096 * 2048;                 // 3072*2048
  u16*   Wot  = Wt  + (size_t)3072 * 2048;                 // 2048*2048
  u16*   qkv  = Wot + (size_t)2048 * 2048;                 // 4096*3072 bf16 (Q|K parts used)
  u16*   Kr   = qkv + (size_t)4096 * 3072;                 // (B,HKV,S,D)
  u16*   Vtb  = Kr  + (size_t)B_ * HKV_ * S_ * D_;         // (B,HKV,D,S) transposed+perm
  u16*   Ob   = Vtb + (size_t)B_ * HKV_ * S_ * D_;         // (B,S,HID)

  // prep #1: cast x + all weight transposes (1 launch)
  prep_cast_weights<<<dim3(18432), 256, 0, stream>>>(x, Wq, Wk, Wv, Wo, xb, Wt, Wot);

  // QKV projection: Q/K -> bf16 qkv; V -> Vt (transposed+permuted) directly
  gemm_bt<1><<<dim3(768), 256, 0, stream>>>(xb, Wt, qkv, Vtb, 4096, 3072, 2048, 32);

  // prep #2: K-RoPE only
  prep_rope_k<<<dim3(2048), 256, 0, stream>>>(qkv, cosb, sinb, Kr);

  // attention: 1024 blocks, panel-XCD swizzle, balanced qt permutation,
  // Q-RoPE fused in prologue (reads qkv directly)
  attn_kernel<<<dim3(1024), 256, 0, stream>>>(qkv, cosb, sinb, Kr, Vtb, Ob);

  // output projection (f32 out)
  gemm_bt<0><<<dim3(512), 256, 0, stream>>>(Ob, Wot, out, nullptr, 4096, 2048, 2048, 32);
}